// Round 4
// baseline (441.756 us; speedup 1.0000x reference)
//
#include <hip/hip_runtime.h>
#include <stdint.h>

typedef __attribute__((ext_vector_type(4))) float f32x4;
typedef __attribute__((ext_vector_type(8))) short short8;
typedef unsigned short u16;
typedef unsigned int u32;

#define DEV static __device__ __forceinline__

DEV u32 fbits(float f) { union { float f; u32 u; } v; v.f = f; return v.u; }
DEV float bits2f(u32 u) { union { u32 u; float f; } v; v.u = u; return v.f; }

// bf16 round-to-nearest-even
DEV u16 f2bf_rne(float f) {
  u32 u = fbits(f);
  u32 r = u + 0x7fffu + ((u >> 16) & 1u);
  return (u16)(r >> 16);
}
DEV u16 f2bf_trunc(float f) { return (u16)(fbits(f) >> 16); }
DEV float bf2f(u16 h) { return bits2f(((u32)h) << 16); }

// split f32 -> hi (RNE) + lo (trunc of residual): hi+lo accurate to ~2^-17 rel
DEV void split2(float f, u16& h, u16& l) {
  h = f2bf_rne(f);
  float r = f - bf2f(h);
  l = f2bf_trunc(r);
}

DEV void gll16(const void* gsrc, char* ldsp) {
  __builtin_amdgcn_global_load_lds(
      (const __attribute__((address_space(1))) u32*)gsrc,
      (__attribute__((address_space(3))) u32*)ldsp,
      16, 0, 0);
}

DEV f32x4 mfma16(short8 a, short8 b, f32x4 c) {
  return __builtin_amdgcn_mfma_f32_16x16x32_bf16(a, b, c, 0, 0, 0);
}

// ---------------------------------------------------------------------------
// K1: C[M][N] = A[M][512] * B[N][512]^T in fp32-emulated (split bf16, 3 MFMA)
// EPI==0: write (scale*C) split into hi/lo bf16 arrays [M][512]   (q, k)
// EPI==1: write bf16(C) into v_t[b][d][s'] layout, m=d, n=global token (v),
//         with the PV contract permutation applied within each 32-col group.
// block 256 thr (4 waves), tile 128x128, BK=64, LDS 64KiB
// ---------------------------------------------------------------------------
template<int EPI>
__global__ __launch_bounds__(256, 1) void proj_gemm(
    const float* __restrict__ A, const float* __restrict__ Bm,
    u16* __restrict__ o0, u16* __restrict__ o1, float scale)
{
  extern __shared__ char smem[];
  const int tid = threadIdx.x;
  const int lane = tid & 63, wv = tid >> 6;
  const int wm = wv & 1, wn = wv >> 1;
  const int lm = lane & 15, lg = lane >> 4;
  const int n0 = blockIdx.x * 128, m0 = blockIdx.y * 128;

  f32x4 acc[4][4] = {};

  for (int k0 = 0; k0 < 512; k0 += 64) {
    __syncthreads();
    #pragma unroll
    for (int i = 0; i < 8; ++i) {
      int c = i * 256 + tid;          // f32x4 chunk 0..2047
      int row = c >> 4, c4 = c & 15;
      f32x4 av = *(const f32x4*)(A + (size_t)(m0 + row) * 512 + (k0 + c4 * 4));
      f32x4 bv = *(const f32x4*)(Bm + (size_t)(n0 + row) * 512 + (k0 + c4 * 4));
      int base = row * 128 + ((((c4 >> 1) ^ (row & 7)) << 4) + (c4 & 1) * 8);
      u16 ah[4], al[4], bh[4], bl[4];
      #pragma unroll
      for (int j = 0; j < 4; ++j) { split2(av[j], ah[j], al[j]); split2(bv[j], bh[j], bl[j]); }
      *(ushort4*)(smem +         base) = make_ushort4(ah[0], ah[1], ah[2], ah[3]);
      *(ushort4*)(smem + 16384 + base) = make_ushort4(al[0], al[1], al[2], al[3]);
      *(ushort4*)(smem + 32768 + base) = make_ushort4(bh[0], bh[1], bh[2], bh[3]);
      *(ushort4*)(smem + 49152 + base) = make_ushort4(bl[0], bl[1], bl[2], bl[3]);
    }
    __syncthreads();
    #pragma unroll
    for (int ks = 0; ks < 2; ++ks) {
      short8 fah[4], fal[4], fbh[4], fbl[4];
      #pragma unroll
      for (int t = 0; t < 4; ++t) {
        int ar = wm * 64 + t * 16 + lm;
        int ac = (((ks * 4 + lg) ^ (ar & 7)) << 4);
        fah[t] = *(const short8*)(smem +         ar * 128 + ac);
        fal[t] = *(const short8*)(smem + 16384 + ar * 128 + ac);
        int br = wn * 64 + t * 16 + lm;
        int bc = (((ks * 4 + lg) ^ (br & 7)) << 4);
        fbh[t] = *(const short8*)(smem + 32768 + br * 128 + bc);
        fbl[t] = *(const short8*)(smem + 49152 + br * 128 + bc);
      }
      #pragma unroll
      for (int mt = 0; mt < 4; ++mt)
        #pragma unroll
        for (int nt = 0; nt < 4; ++nt) {
          acc[mt][nt] = mfma16(fah[mt], fbh[nt], acc[mt][nt]);
          acc[mt][nt] = mfma16(fah[mt], fbl[nt], acc[mt][nt]);
          acc[mt][nt] = mfma16(fal[mt], fbh[nt], acc[mt][nt]);
        }
    }
  }
  // epilogue: C row = (lane>>4)*4 + i, col = lane&15
  #pragma unroll
  for (int mt = 0; mt < 4; ++mt)
    #pragma unroll
    for (int nt = 0; nt < 4; ++nt)
      #pragma unroll
      for (int i = 0; i < 4; ++i) {
        float v = acc[mt][nt][i] * scale;
        int m = m0 + wm * 64 + mt * 16 + lg * 4 + i;
        int n = n0 + wn * 64 + nt * 16 + lm;
        if (EPI == 0) {
          u16 h, l; split2(v, h, l);
          o0[(size_t)m * 512 + n] = h;
          o1[(size_t)m * 512 + n] = l;
        } else {
          // v_t[b][d][s']: permute key r=(n&31) -> col c within its 32-group
          int r = n & 31;
          int cc = ((r >> 2) & 3) * 8 + ((r >> 4) << 2) + (r & 3);
          int n2 = (n & ~31) | cc;
          size_t addr = ((size_t)(n >> 11) << 20) | ((size_t)m << 11) | (size_t)(n2 & 2047);
          o0[addr] = f2bf_rne(v);
        }
      }
}

// ---------------------------------------------------------------------------
// K2: fused flash attention, 8 waves (2/SIMD), kt-split into 2 DECOUPLED
// groups. Group g (waves 4g..4g+3) processes kt = 2t+g; private online
// softmax; end merge via LDS. In-loop sync = GROUP-LOCAL LDS spin barrier
// (ds_add counter + poll), NOT s_barrier -> the two groups' pipelines run
// independently and overlap each other's stalls on the shared SIMDs.
// Per kt: 24 x 8KB chunks (8 K-hi, 8 K-lo interleaved, 8 V), 3 rotating
// buffers per group, depth-1 prefetch, vmcnt(2), ONE group-bar per phase
// (safe: stage target (c+1)%3 != laggard-compute (c-1)%3 != current c%3;
// passing bar(c-1) implies compute(c-2) done, protecting buffer reuse).
// Q-hi in LDS (64K, shared ro); Q-lo in registers (16 short8/lane).
// LDS: QH 64K | G0 3x8K | G1 3x8K | cnt @128K | merge-stats = 129KiB
// ---------------------------------------------------------------------------
#define STG_BASE 65536
#define CNT_OFF  131072
#define MLP_OFF  131584
#define LDS_SZ   132096

DEV void group_bar(char* smem, int g, int lane, int target) {
  int* ca = (int*)(smem + CNT_OFF + g * 4);
  if (lane == 0) atomicAdd(ca, 1);
  volatile int* cp = (volatile int*)ca;
  int v = *cp;
  while (v < target) { __builtin_amdgcn_s_sleep(1); v = *cp; }
}

// chunk c of K-tile kt: c in [0,16): K (even=hi, odd=lo), d-chunk c>>1;
// c in [16,24): V^T d-rows (c-16)*64. All chunks 8KB, 2 gll16/thread.
DEV void stage_chunk8(const u16* __restrict__ kh, const u16* __restrict__ kl,
                      const u16* __restrict__ vt, char* smem, int g, int buf,
                      int b, int kt, int c, int tid256) {
  char* dst = smem + STG_BASE + g * 24576 + buf * 8192;
  if (c < 16) {
    const u16* src = (c & 1) ? kl : kh;
    const size_t kbase = (size_t)b * 2048 * 512 + (size_t)kt * 64 * 512 + (c >> 1) * 64;
    #pragma unroll
    for (int j = 0; j < 2; ++j) {
      int slot = j * 256 + tid256;
      int r = slot >> 3, ch = slot & 7, sc = ch ^ (r & 7);
      gll16(src + kbase + (size_t)r * 512 + sc * 8, dst + slot * 16);
    }
  } else {
    const int cv = c - 16;
    const size_t vbase = (size_t)b * 512 * 2048 + (size_t)(cv * 64) * 2048 + (size_t)kt * 64;
    #pragma unroll
    for (int j = 0; j < 2; ++j) {
      int slot = j * 256 + tid256;
      int r = slot >> 3, ch = slot & 7, sc = ch ^ (r & 7);
      gll16(vt + vbase + (size_t)r * 2048 + sc * 8, dst + slot * 16);
    }
  }
}

__global__ __launch_bounds__(512, 2) void attn_fused(
    const u16* __restrict__ qh, const u16* __restrict__ ql,
    const u16* __restrict__ kh, const u16* __restrict__ kl,
    const u16* __restrict__ vt, float* __restrict__ out)
{
  extern __shared__ char smem[];
  const int tid = threadIdx.x;
  const int lane = tid & 63, wv = tid >> 6;
  const int g = wv >> 2, wg = wv & 3;
  const int lm = lane & 15, lg = lane >> 4;
  const int tid256 = tid & 255;
  const int b = blockIdx.x, qt = blockIdx.y;   // batch fastest -> XCD-local K/V
  const int qrow = wg * 16 + lm;

  if (tid < 2) *((int*)(smem + CNT_OFF) + tid) = 0;

  const size_t qbase = (size_t)(b * 2048 + qt * 64) * 512;
  // ---- stage Q-hi [64][512] bf16 into LDS, swizzled (16B chunk ^= row&7)
  #pragma unroll
  for (int it = 0; it < 8; ++it) {
    int slot = it * 512 + tid;
    int row = slot >> 6, ch = slot & 63;
    int sc = ch ^ (row & 7);
    gll16(qh + qbase + (size_t)row * 512 + sc * 8, smem + slot * 16);
  }
  // ---- Q-lo fragments to registers: qlr[2dc+ks] = cols dc*64+ks*32+lg*8
  short8 qlr[16];
  #pragma unroll
  for (int j = 0; j < 16; ++j)
    qlr[j] = *(const short8*)(ql + qbase + (size_t)qrow * 512 + j * 32 + lg * 8);

  // ---- prologue: stage chunk 0 of this group's first tile (kt=g)
  stage_chunk8(kh, kl, vt, smem, g, 0, b, g, 0, tid256);
  asm volatile("s_waitcnt vmcnt(0)" ::: "memory");
  __syncthreads();

  float m = -3e38f, l = 0.f;
  f32x4 oacc[32] = {};
  short8 pb0 = {}, pb1 = {};
  int barn = 0;

  for (int t = 0; t < 16; ++t) {
    f32x4 sacc[4] = {};
    #pragma unroll
    for (int c = 0; c < 24; ++c) {
      // ---- stage chunk c+1 (wraps to next kt; harmless reload at the end)
      {
        int nc = c + 1, tt = t;
        if (nc == 24) { nc = 0; ++tt; }
        int nkt = 2 * (tt & 15) + g;
        stage_chunk8(kh, kl, vt, smem, g, (c + 1) % 3, b, nkt, nc, tid256);
      }
      // ---- softmax + P repack between QK and PV phases (register-only)
      if (c == 16) {
        float mx = fmaxf(fmaxf(fmaxf(sacc[0][0], sacc[0][1]), fmaxf(sacc[0][2], sacc[0][3])),
                         fmaxf(fmaxf(sacc[1][0], sacc[1][1]), fmaxf(sacc[1][2], sacc[1][3])));
        mx = fmaxf(mx, fmaxf(fmaxf(fmaxf(sacc[2][0], sacc[2][1]), fmaxf(sacc[2][2], sacc[2][3])),
                             fmaxf(fmaxf(sacc[3][0], sacc[3][1]), fmaxf(sacc[3][2], sacc[3][3]))));
        mx = fmaxf(mx, __shfl_xor(mx, 16, 64));
        mx = fmaxf(mx, __shfl_xor(mx, 32, 64));
        if (__any(mx > m)) {          // exact rescale-skip: only when max grows
          float mn = fmaxf(m, mx);
          float alpha = __expf(m - mn);
          m = mn;
          #pragma unroll
          for (int f = 0; f < 32; ++f) {
            oacc[f][0] *= alpha; oacc[f][1] *= alpha;
            oacc[f][2] *= alpha; oacc[f][3] *= alpha;
          }
          l *= alpha;
        }
        float sm = 0.f;
        #pragma unroll
        for (int t4 = 0; t4 < 4; ++t4)
          #pragma unroll
          for (int i = 0; i < 4; ++i) {
            float p = __expf(sacc[t4][i] - m);
            sacc[t4][i] = p;
            sm += p;
          }
        sm += __shfl_xor(sm, 16, 64);
        sm += __shfl_xor(sm, 32, 64);
        l += sm;
        // pure in-lane P repack (contract permutation baked into v_t cols)
        #pragma unroll
        for (int j = 0; j < 4; ++j) {
          pb0[j]     = (short)f2bf_rne(sacc[0][j]);
          pb0[4 + j] = (short)f2bf_rne(sacc[1][j]);
          pb1[j]     = (short)f2bf_rne(sacc[2][j]);
          pb1[4 + j] = (short)f2bf_rne(sacc[3][j]);
        }
      }
      // ---- wait own chunk-c loads (chunk c+1 stays in flight), group sync
      asm volatile("s_waitcnt vmcnt(2)" ::: "memory");
      ++barn;
      group_bar(smem, g, lane, barn * 4);
      __builtin_amdgcn_sched_barrier(0);
      const char* bufp = smem + STG_BASE + g * 24576 + (c % 3) * 8192;
      __builtin_amdgcn_s_setprio(1);
      if (c < 16) {
        const int dc = c >> 1;
        if (!(c & 1)) {
          // K-hi phase: sacc += akh*bqh + akh*bql
          #pragma unroll
          for (int ks = 0; ks < 2; ++ks) {
            int qg = dc * 8 + ks * 4 + lg;
            short8 bqh = *(const short8*)(smem + qrow * 1024 + ((qg ^ (qrow & 7)) << 4));
            short8 bql = qlr[dc * 2 + ks];
            #pragma unroll
            for (int t4 = 0; t4 < 4; ++t4) {
              int krow = t4 * 16 + lm;
              int kc = ((ks * 4 + lg) ^ (krow & 7)) << 4;
              short8 akh = *(const short8*)(bufp + krow * 128 + kc);
              sacc[t4] = mfma16(akh, bqh, sacc[t4]);
              sacc[t4] = mfma16(akh, bql, sacc[t4]);
            }
          }
        } else {
          // K-lo phase: sacc += akl*bqh
          #pragma unroll
          for (int ks = 0; ks < 2; ++ks) {
            int qg = dc * 8 + ks * 4 + lg;
            short8 bqh = *(const short8*)(smem + qrow * 1024 + ((qg ^ (qrow & 7)) << 4));
            #pragma unroll
            for (int t4 = 0; t4 < 4; ++t4) {
              int krow = t4 * 16 + lm;
              int kc = ((ks * 4 + lg) ^ (krow & 7)) << 4;
              short8 akl = *(const short8*)(bufp + krow * 128 + kc);
              sacc[t4] = mfma16(akl, bqh, sacc[t4]);
            }
          }
        }
      } else {
        const int cv = c - 16;
        #pragma unroll
        for (int dt = 0; dt < 4; ++dt) {
          int vrow = dt * 16 + lm;
          short8 av0 = *(const short8*)(bufp + vrow * 128 + ((lg ^ (vrow & 7)) << 4));
          short8 av1 = *(const short8*)(bufp + vrow * 128 + (((4 + lg) ^ (vrow & 7)) << 4));
          f32x4 o = oacc[cv * 4 + dt];
          o = mfma16(av0, pb0, o);
          o = mfma16(av1, pb1, o);
          oacc[cv * 4 + dt] = o;
        }
      }
      __builtin_amdgcn_s_setprio(0);
      __builtin_amdgcn_sched_barrier(0);
    }
  }
  // ---- drain in-flight wrapped stages, then merge the two kt-groups
  asm volatile("s_waitcnt vmcnt(0)" ::: "memory");
  __syncthreads();
  float* mlp = (float*)(smem + MLP_OFF);
  if (g == 1) {
    const int base = wg * 32768;
    #pragma unroll
    for (int f = 0; f < 32; ++f) {
      int d4 = (f * 16 + lg * 4) * 4;                  // byte offset of d0
      *(f32x4*)(smem + base + lm * 2048 + (d4 ^ ((lm & 7) << 4))) = oacc[f];
    }
    if (lg == 0) {
      mlp[(wg * 16 + lm) * 2 + 0] = m;
      mlp[(wg * 16 + lm) * 2 + 1] = l;
    }
  }
  __syncthreads();
  if (g == 0) {
    float m1 = mlp[(wg * 16 + lm) * 2 + 0];
    float l1 = mlp[(wg * 16 + lm) * 2 + 1];
    float mf = fmaxf(m, m1);
    float a0 = __expf(m - mf), a1 = __expf(m1 - mf);
    float linv = 1.0f / (a0 * l + a1 * l1);
    const int s = qt * 64 + wg * 16 + lm;
    float* ob = out + ((size_t)b << 20) + s;
    #pragma unroll
    for (int f = 0; f < 32; ++f) {
      int d4 = (f * 16 + lg * 4) * 4;
      f32x4 o1 = *(const f32x4*)(smem + wg * 32768 + lm * 2048 + (d4 ^ ((lm & 7) << 4)));
      #pragma unroll
      for (int i = 0; i < 4; ++i) {
        int d = f * 16 + lg * 4 + i;
        ob[(size_t)d * 2048] = (a0 * oacc[f][i] + a1 * o1[i]) * linv;
      }
    }
  }
}

// ---------------------------------------------------------------------------
extern "C" void kernel_launch(void* const* d_in, const int* in_sizes, int n_in,
                              void* d_out, int out_size, void* d_ws, size_t ws_size,
                              hipStream_t stream) {
  (void)in_sizes; (void)n_in; (void)out_size; (void)ws_size;
  const float* x  = (const float*)d_in[0];
  const float* Wk = (const float*)d_in[1];
  const float* Wq = (const float*)d_in[2];
  const float* Wv = (const float*)d_in[3];
  float* out = (float*)d_out;

  const size_t SZ = (size_t)16384 * 512;  // elements per [M][512] array
  u16* q_hi = (u16*)d_ws;
  u16* q_lo = q_hi + SZ;
  u16* k_hi = q_lo + SZ;
  u16* k_lo = k_hi + SZ;
  u16* v_t  = k_lo + SZ;                  // [8][512][2048] bf16 (col-permuted)

  (void)hipFuncSetAttribute(reinterpret_cast<const void*>(&proj_gemm<0>),
                            hipFuncAttributeMaxDynamicSharedMemorySize, 65536);
  (void)hipFuncSetAttribute(reinterpret_cast<const void*>(&proj_gemm<1>),
                            hipFuncAttributeMaxDynamicSharedMemorySize, 65536);
  (void)hipFuncSetAttribute(reinterpret_cast<const void*>(&attn_fused),
                            hipFuncAttributeMaxDynamicSharedMemorySize, LDS_SZ);

  dim3 pblk(256), ablk(512);
  // q = 5 * x @ Wq^T (scale folded into q so scores come out pre-scaled)
  proj_gemm<0><<<dim3(4, 128), pblk, 65536, stream>>>(x, Wq, q_hi, q_lo, 5.0f);
  proj_gemm<0><<<dim3(4, 128), pblk, 65536, stream>>>(x, Wk, k_hi, k_lo, 1.0f);
  // v^T via swapped operands: C[d][token] = Wv[d][k] * x[token][k]^T
  proj_gemm<1><<<dim3(128, 4), pblk, 65536, stream>>>(Wv, x, v_t, nullptr, 1.0f);
  attn_fused<<<dim3(8, 32), ablk, LDS_SZ, stream>>>(q_hi, q_lo, k_hi, k_lo, v_t, out);
}

// Round 5
// 412.732 us; speedup vs baseline: 1.0703x; 1.0703x over previous
//
#include <hip/hip_runtime.h>
#include <stdint.h>

typedef __attribute__((ext_vector_type(4))) float f32x4;
typedef __attribute__((ext_vector_type(8))) short short8;
typedef unsigned short u16;
typedef unsigned int u32;

#define DEV static __device__ __forceinline__

DEV u32 fbits(float f) { union { float f; u32 u; } v; v.f = f; return v.u; }
DEV float bits2f(u32 u) { union { u32 u; float f; } v; v.u = u; return v.f; }

// bf16 round-to-nearest-even
DEV u16 f2bf_rne(float f) {
  u32 u = fbits(f);
  u32 r = u + 0x7fffu + ((u >> 16) & 1u);
  return (u16)(r >> 16);
}
DEV u16 f2bf_trunc(float f) { return (u16)(fbits(f) >> 16); }
DEV float bf2f(u16 h) { return bits2f(((u32)h) << 16); }

// split f32 -> hi (RNE) + lo (trunc of residual): hi+lo accurate to ~2^-17 rel
DEV void split2(float f, u16& h, u16& l) {
  h = f2bf_rne(f);
  float r = f - bf2f(h);
  l = f2bf_trunc(r);
}

DEV void gll16(const void* gsrc, char* ldsp) {
  __builtin_amdgcn_global_load_lds(
      (const __attribute__((address_space(1))) u32*)gsrc,
      (__attribute__((address_space(3))) u32*)ldsp,
      16, 0, 0);
}

DEV f32x4 mfma16(short8 a, short8 b, f32x4 c) {
  return __builtin_amdgcn_mfma_f32_16x16x32_bf16(a, b, c, 0, 0, 0);
}

// ---------------------------------------------------------------------------
// K1: C[M][N] = A[M][512] * B[N][512]^T in fp32-emulated (split bf16, 3 MFMA)
// EPI==0: (scale*C) split into hi/lo bf16 row-major arrays [M][512]   (q)
// EPI==1: bf16(C) into v_t[b][d][s'] layout (PV contract-permuted cols) (v)
// EPI==2: hi row-major [M][512]; lo in MFMA-FRAG-MAJOR layout          (k)
//         k_lo2[((b*32+kt)*8+dc)*8 + ks*4+t4][lane][8]  (1KB/frag, lane-contig)
// ---------------------------------------------------------------------------
template<int EPI>
__global__ __launch_bounds__(256, 1) void proj_gemm(
    const float* __restrict__ A, const float* __restrict__ Bm,
    u16* __restrict__ o0, u16* __restrict__ o1, float scale)
{
  extern __shared__ char smem[];
  const int tid = threadIdx.x;
  const int lane = tid & 63, wv = tid >> 6;
  const int wm = wv & 1, wn = wv >> 1;
  const int lm = lane & 15, lg = lane >> 4;
  const int n0 = blockIdx.x * 128, m0 = blockIdx.y * 128;

  f32x4 acc[4][4] = {};

  for (int k0 = 0; k0 < 512; k0 += 64) {
    __syncthreads();
    #pragma unroll
    for (int i = 0; i < 8; ++i) {
      int c = i * 256 + tid;          // f32x4 chunk 0..2047
      int row = c >> 4, c4 = c & 15;
      f32x4 av = *(const f32x4*)(A + (size_t)(m0 + row) * 512 + (k0 + c4 * 4));
      f32x4 bv = *(const f32x4*)(Bm + (size_t)(n0 + row) * 512 + (k0 + c4 * 4));
      int base = row * 128 + ((((c4 >> 1) ^ (row & 7)) << 4) + (c4 & 1) * 8);
      u16 ah[4], al[4], bh[4], bl[4];
      #pragma unroll
      for (int j = 0; j < 4; ++j) { split2(av[j], ah[j], al[j]); split2(bv[j], bh[j], bl[j]); }
      *(ushort4*)(smem +         base) = make_ushort4(ah[0], ah[1], ah[2], ah[3]);
      *(ushort4*)(smem + 16384 + base) = make_ushort4(al[0], al[1], al[2], al[3]);
      *(ushort4*)(smem + 32768 + base) = make_ushort4(bh[0], bh[1], bh[2], bh[3]);
      *(ushort4*)(smem + 49152 + base) = make_ushort4(bl[0], bl[1], bl[2], bl[3]);
    }
    __syncthreads();
    #pragma unroll
    for (int ks = 0; ks < 2; ++ks) {
      short8 fah[4], fal[4], fbh[4], fbl[4];
      #pragma unroll
      for (int t = 0; t < 4; ++t) {
        int ar = wm * 64 + t * 16 + lm;
        int ac = (((ks * 4 + lg) ^ (ar & 7)) << 4);
        fah[t] = *(const short8*)(smem +         ar * 128 + ac);
        fal[t] = *(const short8*)(smem + 16384 + ar * 128 + ac);
        int br = wn * 64 + t * 16 + lm;
        int bc = (((ks * 4 + lg) ^ (br & 7)) << 4);
        fbh[t] = *(const short8*)(smem + 32768 + br * 128 + bc);
        fbl[t] = *(const short8*)(smem + 49152 + br * 128 + bc);
      }
      #pragma unroll
      for (int mt = 0; mt < 4; ++mt)
        #pragma unroll
        for (int nt = 0; nt < 4; ++nt) {
          acc[mt][nt] = mfma16(fah[mt], fbh[nt], acc[mt][nt]);
          acc[mt][nt] = mfma16(fah[mt], fbl[nt], acc[mt][nt]);
          acc[mt][nt] = mfma16(fal[mt], fbh[nt], acc[mt][nt]);
        }
    }
  }
  // epilogue: C row = (lane>>4)*4 + i, col = lane&15
  #pragma unroll
  for (int mt = 0; mt < 4; ++mt)
    #pragma unroll
    for (int nt = 0; nt < 4; ++nt)
      #pragma unroll
      for (int i = 0; i < 4; ++i) {
        float v = acc[mt][nt][i] * scale;
        int m = m0 + wm * 64 + mt * 16 + lg * 4 + i;
        int n = n0 + wn * 64 + nt * 16 + lm;
        if (EPI == 0) {
          u16 h, l; split2(v, h, l);
          o0[(size_t)m * 512 + n] = h;
          o1[(size_t)m * 512 + n] = l;
        } else if (EPI == 1) {
          // v_t[b][d][s']: permute key r=(n&31) -> col c within its 32-group
          int r = n & 31;
          int cc = ((r >> 2) & 3) * 8 + ((r >> 4) << 2) + (r & 3);
          int n2 = (n & ~31) | cc;
          size_t addr = ((size_t)(n >> 11) << 20) | ((size_t)m << 11) | (size_t)(n2 & 2047);
          o0[addr] = f2bf_rne(v);
        } else {
          // k: hi row-major, lo frag-major for direct per-lane MFMA loads
          u16 h, lo; split2(v, h, lo);
          o0[(size_t)m * 512 + n] = h;
          int b2 = m >> 11, s = m & 2047;
          int kt = s >> 6, t4s = (s >> 4) & 3, lma = s & 15;
          int dc = n >> 6, ks = (n >> 5) & 1, lga = (n >> 3) & 3, j = n & 7;
          size_t idx = (((size_t)(b2 * 32 + kt) * 8 + dc) * 8 + (ks * 4 + t4s)) * 512
                       + (size_t)(lga * 16 + lma) * 8 + j;
          o1[idx] = lo;
        }
      }
}

// ---------------------------------------------------------------------------
// K2: fused flash attention. 4 waves, QBLK=64 (16 q-cols/wave, swapped QK^T).
// LDS streams reduced to K-hi + V + Q-hi only; K-LO IS NEVER IN LDS: lh-pass
// A-frags are per-lane global dwordx4 loads from the frag-major k_lo2 array
// (L2/L3-resident), software-pipelined one dc ahead with counted vmcnt.
// Per kt: 8 phases (4 K-hi chunks [64k][128d], 4 V chunks [128d][64k]),
// 2 x 16KB rotating buffers, ONE s_barrier per phase (stage(c+1) issue ->
// compute(c) -> vmcnt -> barrier is hazard-free with 2 bufs).
// LDS: QH 64K | 2 x 16K staging = 96KiB.
// ---------------------------------------------------------------------------
#define STG_OFF 65536

DEV void stage(const u16* __restrict__ kh, const u16* __restrict__ vt,
               char* smem, int b, int kt, int c, int tid) {
  char* dst = smem + STG_OFF + (c & 1) * 16384;
  if (c < 4) {  // K-hi chunk [64k][128d], d in [c*128, c*128+128)
    const size_t base = (size_t)(b * 2048 + kt * 64) * 512 + c * 128;
    #pragma unroll
    for (int j = 0; j < 4; ++j) {
      int slot = j * 256 + tid;
      int r = slot >> 4, ch = slot & 15, sc = ch ^ (r & 7);
      gll16(kh + base + (size_t)r * 512 + sc * 8, dst + slot * 16);
    }
  } else {      // V chunk [128d][64k], d-rows (c-4)*128
    const size_t base = (size_t)b * 512 * 2048 + (size_t)((c - 4) * 128) * 2048
                        + (size_t)kt * 64;
    #pragma unroll
    for (int j = 0; j < 4; ++j) {
      int slot = j * 256 + tid;
      int r = slot >> 3, ch = slot & 7, sc = ch ^ (r & 7);
      gll16(vt + base + (size_t)r * 2048 + sc * 8, dst + slot * 16);
    }
  }
}

__global__ __launch_bounds__(256, 1) void attn_fused(
    const u16* __restrict__ qh, const u16* __restrict__ ql,
    const u16* __restrict__ kh, const u16* __restrict__ kl2,
    const u16* __restrict__ vt, float* __restrict__ out)
{
  extern __shared__ char smem[];
  const int tid = threadIdx.x;
  const int lane = tid & 63, wv = tid >> 6;
  const int lm = lane & 15, lg = lane >> 4;
  const int b = blockIdx.x, qt = blockIdx.y;   // batch fastest -> XCD-local K/V
  const int qrow = wv * 16 + lm;

  const size_t qbase = (size_t)(b * 2048 + qt * 64) * 512;
  // ---- stage Q-hi [64][512] bf16 into LDS, swizzled (16B chunk ^= row&7)
  #pragma unroll
  for (int it = 0; it < 16; ++it) {
    int slot = it * 256 + tid;
    int row = slot >> 6, ch = slot & 63;
    int sc = ch ^ (row & 7);
    gll16(qh + qbase + (size_t)row * 512 + sc * 8, smem + slot * 16);
  }
  // ---- Q-lo fragments to registers: qlr[2dc+ks] = cols dc*64+ks*32+lg*8
  short8 qlr[16];
  #pragma unroll
  for (int j = 0; j < 16; ++j)
    qlr[j] = *(const short8*)(ql + qbase + (size_t)qrow * 512 + j * 32 + lg * 8);

  // ---- prologue: stage chunk0 (buf0) + load aklA (kt0, dc0)
  stage(kh, vt, smem, b, 0, 0, tid);
  short8 aklA[8], aklB[8], aklN[8];
  {
    const size_t fb = ((size_t)(b * 32 + 0) * 8 + 0) * 4096;
    #pragma unroll
    for (int f = 0; f < 8; ++f)
      aklA[f] = *(const short8*)(kl2 + fb + (size_t)f * 512 + lane * 8);
  }
  asm volatile("s_waitcnt vmcnt(0)" ::: "memory");
  __syncthreads();

  float m = -3e38f, l = 0.f;
  f32x4 oacc[32] = {};
  short8 pb0 = {}, pb1 = {};

  for (int kt = 0; kt < 32; ++kt) {
    f32x4 sacc[4] = {};
    const size_t fkt = (size_t)(b * 32 + kt) * 8;
    #pragma unroll
    for (int c = 0; c < 8; ++c) {
      // ---- stage chunk c+1 (wraps to kt+1 chunk0 at c==7)
      {
        int nc = c + 1, nk = kt;
        if (nc == 8) { nc = 0; nk = (kt + 1) & 31; }
        stage(kh, vt, smem, b, nk, nc, tid);
      }
      __builtin_amdgcn_sched_barrier(0);
      const char* bufp = smem + STG_OFF + (c & 1) * 16384;
      if (c < 4) {
        const int dcA = c * 2, dcB = c * 2 + 1;
        // issue aklB (this phase's second dc)
        {
          const size_t fbB = (fkt + dcB) * 4096;
          #pragma unroll
          for (int f = 0; f < 8; ++f)
            aklB[f] = *(const short8*)(kl2 + fbB + (size_t)f * 512 + lane * 8);
        }
        __builtin_amdgcn_sched_barrier(0);
        // dcA: hh + hl (K-hi from LDS, Q-lo from regs)
        short8 bqhA[2];
        #pragma unroll
        for (int ks = 0; ks < 2; ++ks) {
          int qg = dcA * 8 + ks * 4 + lg;
          bqhA[ks] = *(const short8*)(smem + qrow * 1024 + ((qg ^ (qrow & 7)) << 4));
          #pragma unroll
          for (int t4 = 0; t4 < 4; ++t4) {
            int krow = t4 * 16 + lm;
            int cc = ks * 4 + lg;                 // dc_loc = 0
            short8 akh = *(const short8*)(bufp + krow * 256 + ((cc ^ (krow & 7)) << 4));
            sacc[t4] = mfma16(akh, bqhA[ks], sacc[t4]);
            sacc[t4] = mfma16(akh, qlr[dcA * 2 + ks], sacc[t4]);
          }
        }
        asm volatile("s_waitcnt vmcnt(12)" ::: "memory");  // retire aklA
        __builtin_amdgcn_sched_barrier(0);
        #pragma unroll
        for (int ks = 0; ks < 2; ++ks)
          #pragma unroll
          for (int t4 = 0; t4 < 4; ++t4)
            sacc[t4] = mfma16(aklA[ks * 4 + t4], bqhA[ks], sacc[t4]);
        __builtin_amdgcn_sched_barrier(0);
        // issue aklN (next K-phase's first dc; kt+1 dc0 at c==3)
        {
          int nk = (c < 3) ? kt : ((kt + 1) & 31);
          int ndc = (c < 3) ? dcA + 2 : 0;
          const size_t fbN = ((size_t)(b * 32 + nk) * 8 + ndc) * 4096;
          #pragma unroll
          for (int f = 0; f < 8; ++f)
            aklN[f] = *(const short8*)(kl2 + fbN + (size_t)f * 512 + lane * 8);
        }
        __builtin_amdgcn_sched_barrier(0);
        // dcB: hh + hl
        short8 bqhB[2];
        #pragma unroll
        for (int ks = 0; ks < 2; ++ks) {
          int qg = dcB * 8 + ks * 4 + lg;
          bqhB[ks] = *(const short8*)(smem + qrow * 1024 + ((qg ^ (qrow & 7)) << 4));
          #pragma unroll
          for (int t4 = 0; t4 < 4; ++t4) {
            int krow = t4 * 16 + lm;
            int cc = 8 + ks * 4 + lg;             // dc_loc = 1
            short8 akh = *(const short8*)(bufp + krow * 256 + ((cc ^ (krow & 7)) << 4));
            sacc[t4] = mfma16(akh, bqhB[ks], sacc[t4]);
            sacc[t4] = mfma16(akh, qlr[dcB * 2 + ks], sacc[t4]);
          }
        }
        asm volatile("s_waitcnt vmcnt(8)" ::: "memory");   // retire gll(c+1)+aklB
        __builtin_amdgcn_sched_barrier(0);
        #pragma unroll
        for (int ks = 0; ks < 2; ++ks)
          #pragma unroll
          for (int t4 = 0; t4 < 4; ++t4)
            sacc[t4] = mfma16(aklB[ks * 4 + t4], bqhB[ks], sacc[t4]);
        __builtin_amdgcn_sched_barrier(0);
        #pragma unroll
        for (int f = 0; f < 8; ++f) aklA[f] = aklN[f];
        // ---- softmax + P repack after the last QK phase (register-only)
        if (c == 3) {
          float mx = fmaxf(fmaxf(fmaxf(sacc[0][0], sacc[0][1]), fmaxf(sacc[0][2], sacc[0][3])),
                           fmaxf(fmaxf(sacc[1][0], sacc[1][1]), fmaxf(sacc[1][2], sacc[1][3])));
          mx = fmaxf(mx, fmaxf(fmaxf(fmaxf(sacc[2][0], sacc[2][1]), fmaxf(sacc[2][2], sacc[2][3])),
                               fmaxf(fmaxf(sacc[3][0], sacc[3][1]), fmaxf(sacc[3][2], sacc[3][3]))));
          mx = fmaxf(mx, __shfl_xor(mx, 16, 64));
          mx = fmaxf(mx, __shfl_xor(mx, 32, 64));
          if (__any(mx > m)) {        // exact rescale-skip: only when max grows
            float mn = fmaxf(m, mx);
            float alpha = __expf(m - mn);
            m = mn;
            #pragma unroll
            for (int f = 0; f < 32; ++f) {
              oacc[f][0] *= alpha; oacc[f][1] *= alpha;
              oacc[f][2] *= alpha; oacc[f][3] *= alpha;
            }
            l *= alpha;
          }
          float sm = 0.f;
          #pragma unroll
          for (int t4 = 0; t4 < 4; ++t4)
            #pragma unroll
            for (int i = 0; i < 4; ++i) {
              float p = __expf(sacc[t4][i] - m);
              sacc[t4][i] = p;
              sm += p;
            }
          sm += __shfl_xor(sm, 16, 64);
          sm += __shfl_xor(sm, 32, 64);
          l += sm;
          // pure in-lane P repack (contract permutation baked into v_t cols)
          #pragma unroll
          for (int j = 0; j < 4; ++j) {
            pb0[j]     = (short)f2bf_rne(sacc[0][j]);
            pb0[4 + j] = (short)f2bf_rne(sacc[1][j]);
            pb1[j]     = (short)f2bf_rne(sacc[2][j]);
            pb1[4 + j] = (short)f2bf_rne(sacc[3][j]);
          }
        }
      } else {
        // ---- PV phase: O^T[d][s] += V^T[d][k] * P, chunk (c-4) = 128 d-rows
        const int cv = c - 4;
        #pragma unroll
        for (int dt = 0; dt < 8; ++dt) {
          int vrow = dt * 16 + lm;
          short8 av0 = *(const short8*)(bufp + vrow * 128 + ((lg ^ (vrow & 7)) << 4));
          short8 av1 = *(const short8*)(bufp + vrow * 128 + (((4 + lg) ^ (vrow & 7)) << 4));
          f32x4 o = oacc[cv * 8 + dt];
          o = mfma16(av0, pb0, o);
          o = mfma16(av1, pb1, o);
          oacc[cv * 8 + dt] = o;
        }
        asm volatile("s_waitcnt vmcnt(0)" ::: "memory");
        __builtin_amdgcn_sched_barrier(0);
      }
      __builtin_amdgcn_s_barrier();
      __builtin_amdgcn_sched_barrier(0);
    }
  }
  // ---- finalize: divide by l (lane-local), coalesced O^T store
  float linv = 1.0f / l;
  const int s = qt * 64 + wv * 16 + lm;
  float* ob = out + ((size_t)b << 20) + s;
  #pragma unroll
  for (int f = 0; f < 32; ++f)
    #pragma unroll
    for (int i = 0; i < 4; ++i) {
      int d = f * 16 + lg * 4 + i;
      ob[(size_t)d * 2048] = oacc[f][i] * linv;
    }
}

// ---------------------------------------------------------------------------
extern "C" void kernel_launch(void* const* d_in, const int* in_sizes, int n_in,
                              void* d_out, int out_size, void* d_ws, size_t ws_size,
                              hipStream_t stream) {
  (void)in_sizes; (void)n_in; (void)out_size; (void)ws_size;
  const float* x  = (const float*)d_in[0];
  const float* Wk = (const float*)d_in[1];
  const float* Wq = (const float*)d_in[2];
  const float* Wv = (const float*)d_in[3];
  float* out = (float*)d_out;

  const size_t SZ = (size_t)16384 * 512;  // elements per [M][512] array
  u16* q_hi  = (u16*)d_ws;
  u16* q_lo  = q_hi + SZ;
  u16* k_hi  = q_lo + SZ;
  u16* k_lo2 = k_hi + SZ;                 // frag-major K-lo
  u16* v_t   = k_lo2 + SZ;                // [8][512][2048] bf16 (col-permuted)

  (void)hipFuncSetAttribute(reinterpret_cast<const void*>(&proj_gemm<0>),
                            hipFuncAttributeMaxDynamicSharedMemorySize, 65536);
  (void)hipFuncSetAttribute(reinterpret_cast<const void*>(&proj_gemm<1>),
                            hipFuncAttributeMaxDynamicSharedMemorySize, 65536);
  (void)hipFuncSetAttribute(reinterpret_cast<const void*>(&proj_gemm<2>),
                            hipFuncAttributeMaxDynamicSharedMemorySize, 65536);
  (void)hipFuncSetAttribute(reinterpret_cast<const void*>(&attn_fused),
                            hipFuncAttributeMaxDynamicSharedMemorySize, 98304);

  dim3 pblk(256), ablk(256);
  // q = 5 * x @ Wq^T (scale folded into q so scores come out pre-scaled)
  proj_gemm<0><<<dim3(4, 128), pblk, 65536, stream>>>(x, Wq, q_hi, q_lo, 5.0f);
  proj_gemm<2><<<dim3(4, 128), pblk, 65536, stream>>>(x, Wk, k_hi, k_lo2, 1.0f);
  // v^T via swapped operands: C[d][token] = Wv[d][k] * x[token][k]^T
  proj_gemm<1><<<dim3(128, 4), pblk, 65536, stream>>>(Wv, x, v_t, nullptr, 1.0f);
  attn_fused<<<dim3(8, 32), ablk, 98304, stream>>>(q_hi, q_lo, k_hi, k_lo2, v_t, out);
}